// Round 3
// baseline (348.925 us; speedup 1.0000x reference)
//
#include <hip/hip_runtime.h>

// out[(b*N + n)*D + c][s] = q[b][s][c] * w[n][c]
// B=8, S=2048, D=256, N=20, fp32 in/out.
// R0: dur = harness poison-fill (~217 us @ 6.2 TB/s, fixed) + kernel (~122 us
//     @ ~2.9 TB/s effective).
// R2 post-mortem: 2->4 blocks/CU + nt stores = NEUTRAL. Concurrency is not
//     the limiter.
// R3 theory: per-wave store streams were 1-2 KB bursts jumping 8-16 KB every
//     instruction, spread over all 320 MB at once -> DRAM row-buffer thrash /
//     L2 dirty-evict scrambling. Fill wins because each wave writes long
//     sequential runs. Fix: stage the FULL 8 KB output row (TS=2048, TC=8) and
//     give each wave whole rows in flat (n,c) order -> contiguous 64 KB runs
//     per wave (8 rows x 8 KB within one n).

namespace {
constexpr int kB = 8;
constexpr int kS = 2048;
constexpr int kD = 256;
constexpr int kN = 20;
constexpr int TC = 8;            // c-tile
constexpr int NSPLIT = 2;        // n-split across blocks
constexpr int NPB = kN / NSPLIT; // 10 classes per block
constexpr int PTS = kS + 4;      // 2052: +4 pad keeps 16B alignment, breaks
                                 // pow2 banking (row stride % 32 banks = 4)

typedef float v4f __attribute__((ext_vector_type(4)));  // native vec for nt store
}

__global__ __launch_bounds__(256)
void frw_kernel(const float* __restrict__ q, const float* __restrict__ w,
                float* __restrict__ out) {
  const int c0 = blockIdx.x * TC;
  const int b  = blockIdx.y >> 1;
  const int n0 = (blockIdx.y & 1) * NPB;
  const int t  = threadIdx.x;

  __shared__ float tile[TC][PTS];  // [c][s] — full 2048-wide output rows
  __shared__ float ws[NPB][TC];

  // Preload 10x8 slice of w (80 floats).
  if (t < NPB * TC) {
    ws[t / TC][t % TC] = w[(n0 + t / TC) * kD + c0 + (t % TC)];
  }

  // Load 2048(s) x 8(c) tile of q. Two lanes cover one s-row (32 B),
  // 256 threads cover 128 s-rows per pass, 16 passes.
  {
    const int lane2 = t & 1;
    const int srow  = t >> 1;        // 0..127
    const int cvec  = lane2 * 4;
#pragma unroll
    for (int k = 0; k < 16; ++k) {
      const int ss = srow + k * 128;
      const float4 v = *reinterpret_cast<const float4*>(
          &q[((size_t)b * kS + (size_t)ss) * kD + (c0 + cvec)]);
      tile[cvec + 0][ss] = v.x;   // 2-way LDS bank aliasing: free
      tile[cvec + 1][ss] = v.y;
      tile[cvec + 2][ss] = v.z;
      tile[cvec + 3][ss] = v.w;
    }
  }
  __syncthreads();

  // Write phase: each wave owns 20 whole (n,c) rows in flat order.
  // k-inner walks one 8 KB row sequentially (8 x 1 KB store instrs);
  // consecutive rows within one n are address-adjacent -> 64 KB runs.
  const int wv   = t >> 6;           // wave 0..3
  const int lane = t & 63;
  for (int i = 0; i < 20; ++i) {
    const int row = wv * 20 + i;     // 0..79
    const int nn  = row >> 3;        // row / TC
    const int cc  = row & 7;         // row % TC
    const float sc = ws[nn][cc];     // wave-uniform -> LDS broadcast
    const size_t obase =
        (((size_t)(b * kN + n0 + nn)) * kD + (size_t)(c0 + cc)) * (size_t)kS;
#pragma unroll
    for (int k = 0; k < 8; ++k) {
      const int s = k * 256 + lane * 4;
      const float4 v = *reinterpret_cast<const float4*>(&tile[cc][s]);
      v4f o;
      o.x = v.x * sc;
      o.y = v.y * sc;
      o.z = v.z * sc;
      o.w = v.w * sc;
      __builtin_nontemporal_store(o, reinterpret_cast<v4f*>(&out[obase + s]));
    }
  }
}

extern "C" void kernel_launch(void* const* d_in, const int* in_sizes, int n_in,
                              void* d_out, int out_size, void* d_ws, size_t ws_size,
                              hipStream_t stream) {
  const float* q = (const float*)d_in[0];  // (B, S, D)
  const float* w = (const float*)d_in[1];  // (N, D)
  float* out = (float*)d_out;              // (B*N, D, S)

  dim3 grid(kD / TC, kB * NSPLIT, 1);  // 32 x 16 = 512 blocks, 2/CU
  frw_kernel<<<grid, 256, 0, stream>>>(q, w, out);
}